// Round 1
// baseline (163.899 us; speedup 1.0000x reference)
//
#include <hip/hip_runtime.h>

#define BB 32
#define DD 8
#define HH 128
#define WW 128
#define KK 256
#define HW (HH*WW)                 // 16384
#define NPIX (BB*HW)               // 524288
#define Y_OFF   ((size_t)BB*DD*HW)           // 4194304
#define REP_OFF (Y_OFF + NPIX)               // 4718592
#define LOSS_OFF (REP_OFF + (size_t)NPIX*KK) // 138936320

// ---------------- kernel 1: per-pixel VQ ----------------
__global__ __launch_bounds__(256) void vq_main_kernel(
    const float* __restrict__ q, const float* __restrict__ cb,
    float* __restrict__ emb, float* __restrict__ yf,
    int* __restrict__ hist, float* __restrict__ partial)
{
    __shared__ float scb[KK*DD];   // 8 KB codebook
    __shared__ float sc2[KK];      // ||c||^2
    __shared__ int   shist[KK];
    __shared__ float swred[4];

    const int tid = threadIdx.x;

    // codebook -> LDS (2048 floats = 512 float4, 2 per thread)
    const float4* cb4 = (const float4*)cb;
    ((float4*)scb)[tid]       = cb4[tid];
    ((float4*)scb)[tid + 256] = cb4[tid + 256];
    shist[tid] = 0;
    __syncthreads();
    {
        const float* c = &scb[tid*DD];
        sc2[tid] = ((c[0]*c[0] + c[1]*c[1]) + (c[2]*c[2] + c[3]*c[3]))
                 + ((c[4]*c[4] + c[5]*c[5]) + (c[6]*c[6] + c[7]*c[7]));
    }
    __syncthreads();

    const int p  = blockIdx.x * 256 + tid;
    const int b  = p >> 14;            // / HW
    const int hw = p & (HW - 1);
    const float* qp = q + (size_t)b * (DD*HW) + hw;

    float xs[DD];
#pragma unroll
    for (int d = 0; d < DD; ++d) xs[d] = qp[d * HW];
    const float xn = ((xs[0]*xs[0] + xs[1]*xs[1]) + (xs[2]*xs[2] + xs[3]*xs[3]))
                   + ((xs[4]*xs[4] + xs[5]*xs[5]) + (xs[6]*xs[6] + xs[7]*xs[7]));

    float best  = -3.4e38f;
    int   ybest = 0;
#pragma unroll 4
    for (int k = 0; k < KK; ++k) {
        const float* c = &scb[k*DD];
        float dot = 0.f;
#pragma unroll
        for (int d = 0; d < DD; ++d) dot = fmaf(xs[d], c[d], dot);
        // same arithmetic shape as reference: -0.5*((x2 - 2*xc) + c2)
        float s = -0.5f * ((xn - 2.0f*dot) + sc2[k]);
        if (s > best) { best = s; ybest = k; }   // strict > => first index wins ties
    }

    // embedding write + squared-error (recomputed like the reference)
    float err = 0.f;
    const float* cy = &scb[ybest*DD];
    float* ep = emb + (size_t)b * (DD*HW) + hw;
#pragma unroll
    for (int d = 0; d < DD; ++d) {
        float cv = cy[d];
        ep[d*HW] = cv;
        float dd = cv - xs[d];
        err = fmaf(dd, dd, err);
    }
    yf[p] = (float)ybest;
    atomicAdd(&shist[ybest], 1);

    // deterministic block reduction of err
#pragma unroll
    for (int off = 32; off; off >>= 1)
        err += __shfl_down(err, off, 64);
    if ((tid & 63) == 0) swred[tid >> 6] = err;
    __syncthreads();
    if (tid == 0)
        partial[blockIdx.x] = (swred[0] + swred[1]) + (swred[2] + swred[3]);
    // shist complete after the barrier above
    atomicAdd(&hist[tid], shist[tid]);
}

// ---------------- kernel 2: one-hot representation fill ----------------
__global__ __launch_bounds__(256) void vq_rep_kernel(
    const float* __restrict__ yf, float4* __restrict__ rep)
{
    const int idx = blockIdx.x * 256 + threadIdx.x; // float4 index, 33554432 total
    const int p   = idx >> 6;                       // 64 float4 per pixel row
    const int q4  = idx & 63;
    const int y   = (int)yf[p];                     // wave-uniform load
    float4 v = make_float4(0.f, 0.f, 0.f, 0.f);
    if ((y >> 2) == q4) (&v.x)[y & 3] = 1.0f;
    rep[idx] = v;
}

// ---------------- kernel 3: finalize scalars ----------------
__global__ __launch_bounds__(256) void vq_final_kernel(
    const float* __restrict__ partial, const int* __restrict__ hist,
    float* __restrict__ outp)
{
    const int tid = threadIdx.x;
    __shared__ double sred[4];
    __shared__ double shy[4];

    double s = 0.0;
#pragma unroll
    for (int i = 0; i < 8; ++i) s += (double)partial[tid * 8 + i];
#pragma unroll
    for (int off = 32; off; off >>= 1)
        s += __shfl_down(s, off, 64);
    if ((tid & 63) == 0) sred[tid >> 6] = s;

    float c  = (float)hist[tid];
    float py = c * (1.0f / 524288.0f);
    double ht = (double)(py * log2f(py + 1e-10f));
#pragma unroll
    for (int off = 32; off; off >>= 1)
        ht += __shfl_down(ht, off, 64);
    if ((tid & 63) == 0) shy[tid >> 6] = ht;
    __syncthreads();

    if (tid == 0) {
        double S  = (sred[0] + sred[1]) + (sred[2] + sred[3]);
        double Hy = (shy[0]  + shy[1])  + (shy[2]  + shy[3]);
        // loss = 0.5*(0.25*S/4096 + S/4096) = 0.625 * S / 4096
        outp[0] = (float)(0.625 * S / 4096.0);
        outp[1] = (float)(-Hy);
        outp[2] = 0.0f;
    }
}

extern "C" void kernel_launch(void* const* d_in, const int* in_sizes, int n_in,
                              void* d_out, int out_size, void* d_ws, size_t ws_size,
                              hipStream_t stream)
{
    const float* q  = (const float*)d_in[0];
    const float* cb = (const float*)d_in[1];
    float* out = (float*)d_out;

    float*  emb = out;                    // [B,D,H,W]
    float*  yf  = out + Y_OFF;            // [B,H,W] as float
    float4* rep = (float4*)(out + REP_OFF); // [B,H,W,K]
    float*  sc  = out + LOSS_OFF;         // loss, Hy, Hyx

    int*   hist    = (int*)d_ws;          // 256 ints
    float* partial = (float*)d_ws + 256;  // 2048 floats

    hipMemsetAsync(d_ws, 0, 1024, stream);                       // zero hist
    vq_main_kernel<<<NPIX/256, 256, 0, stream>>>(q, cb, emb, yf, hist, partial);
    vq_rep_kernel<<<(NPIX*KK/4)/256, 256, 0, stream>>>(yf, rep); // 131072 blocks
    vq_final_kernel<<<1, 256, 0, stream>>>(partial, hist, sc);
}

// Round 2
// 153.538 us; speedup vs baseline: 1.0675x; 1.0675x over previous
//
#include <hip/hip_runtime.h>

#define DD 8
#define HW 16384
#define KK 256
#define NPIX 524288
#define PPB 1024                       // pixels per block
#define NBLK (NPIX/PPB)                // 512 blocks

#define Y_OFF    4194304UL             // B*D*H*W
#define REP_OFF  4718592UL             // + B*H*W
#define LOSS_OFF 138936320UL           // + B*H*W*K

// ---------------- fused kernel: zero-fill overlapped with argmax ----------------
__global__ __launch_bounds__(256) void vq_fused_kernel(
    const float* __restrict__ q, const float* __restrict__ cb,
    float* __restrict__ emb, float* __restrict__ yf,
    float* __restrict__ rep,
    int* __restrict__ hist, float* __restrict__ partial)
{
    __shared__ float scb[KK*DD];   // 8 KB codebook
    __shared__ float sc2[KK];      // ||c||^2
    __shared__ int   shist[KK];
    __shared__ float swred[4];

    const int tid = threadIdx.x;

    const float4* cb4 = (const float4*)cb;
    ((float4*)scb)[tid]       = cb4[tid];
    ((float4*)scb)[tid + 256] = cb4[tid + 256];
    shist[tid] = 0;
    __syncthreads();
    {
        const float* c = &scb[tid*DD];
        sc2[tid] = ((c[0]*c[0] + c[1]*c[1]) + (c[2]*c[2] + c[3]*c[3]))
                 + ((c[4]*c[4] + c[5]*c[5]) + (c[6]*c[6] + c[7]*c[7]));
    }
    __syncthreads();

    const int pixBase = blockIdx.x * PPB;
    const int b   = pixBase >> 14;          // block lies inside one image
    const int hwB = pixBase & (HW - 1);
    const float* qb = q + (size_t)b * (DD*HW);

    // load 4 pixels per thread (coalesced per d-plane)
    float xs[4][DD];
    float xn[4];
#pragma unroll
    for (int i = 0; i < 4; ++i) {
        const int hw = hwB + i*256 + tid;
#pragma unroll
        for (int d = 0; d < DD; ++d) xs[i][d] = qb[d*HW + hw];
        xn[i] = ((xs[i][0]*xs[i][0] + xs[i][1]*xs[i][1]) + (xs[i][2]*xs[i][2] + xs[i][3]*xs[i][3]))
              + ((xs[i][4]*xs[i][4] + xs[i][5]*xs[i][5]) + (xs[i][6]*xs[i][6] + xs[i][7]*xs[i][7]));
    }

    // argmax over 256 codes; t = (x2 - 2xc) + c2 compared with strict < is
    // bit-order-identical to s = -0.5*t compared with strict > (exact *-0.5).
    float best[4] = {3.4e38f, 3.4e38f, 3.4e38f, 3.4e38f};
    int   yb[4]   = {0, 0, 0, 0};

    const float4* scb4 = (const float4*)scb;
    float4* zp = (float4*)rep + (size_t)blockIdx.x * (PPB * (KK/4)) + tid;
    const float4 z4 = make_float4(0.f, 0.f, 0.f, 0.f);

    for (int k = 0; k < KK; ++k) {
        const float4 c01 = scb4[2*k];
        const float4 c23 = scb4[2*k + 1];
        const float  c2k = sc2[k];
#pragma unroll
        for (int i = 0; i < 4; ++i) {
            float dot = 0.f;
            dot = fmaf(xs[i][0], c01.x, dot);
            dot = fmaf(xs[i][1], c01.y, dot);
            dot = fmaf(xs[i][2], c01.z, dot);
            dot = fmaf(xs[i][3], c01.w, dot);
            dot = fmaf(xs[i][4], c23.x, dot);
            dot = fmaf(xs[i][5], c23.y, dot);
            dot = fmaf(xs[i][6], c23.z, dot);
            dot = fmaf(xs[i][7], c23.w, dot);
            const float t = (xn[i] - 2.0f*dot) + c2k;
            if (t < best[i]) { best[i] = t; yb[i] = k; }  // first index wins ties
        }
        // overlap the 537 MB one-hot zero-fill with compute:
        // one coalesced float4 store per thread per iteration covers the
        // block's whole rep region (1024 px * 64 f4 = 256 iters * 256 thr).
        zp[k << 8] = z4;
    }

    __syncthreads();   // compiler drains vmcnt(0) before s_barrier:
                       // zero-fill globally ordered before the 1.0 scatter below

    float err = 0.f;
#pragma unroll
    for (int i = 0; i < 4; ++i) {
        const int p  = pixBase + i*256 + tid;
        const int hw = hwB + i*256 + tid;
        const int y  = yb[i];
        const float* cy = &scb[y*DD];
        float e = 0.f;
#pragma unroll
        for (int d = 0; d < DD; ++d) {
            const float cv = cy[d];
            emb[(size_t)b*(DD*HW) + d*HW + hw] = cv;
            const float dd = cv - xs[i][d];
            e = fmaf(dd, dd, e);
        }
        err += e;
        yf[p] = (float)y;
        rep[(size_t)p * KK + y] = 1.0f;   // scatter the ones (~1 dword/pixel)
        atomicAdd(&shist[y], 1);
    }

    // deterministic block reduction of err
#pragma unroll
    for (int off = 32; off; off >>= 1)
        err += __shfl_down(err, off, 64);
    if ((tid & 63) == 0) swred[tid >> 6] = err;
    __syncthreads();
    if (tid == 0)
        partial[blockIdx.x] = (swred[0] + swred[1]) + (swred[2] + swred[3]);
    atomicAdd(&hist[tid], shist[tid]);   // shist complete after barrier above
}

// ---------------- finalize scalars ----------------
__global__ __launch_bounds__(256) void vq_final_kernel(
    const float* __restrict__ partial, const int* __restrict__ hist,
    float* __restrict__ outp)
{
    const int tid = threadIdx.x;
    __shared__ double sred[4];
    __shared__ double shy[4];

    double s = (double)partial[tid] + (double)partial[tid + 256];
#pragma unroll
    for (int off = 32; off; off >>= 1)
        s += __shfl_down(s, off, 64);
    if ((tid & 63) == 0) sred[tid >> 6] = s;

    float c  = (float)hist[tid];
    float py = c * (1.0f / 524288.0f);
    double ht = (double)(py * log2f(py + 1e-10f));
#pragma unroll
    for (int off = 32; off; off >>= 1)
        ht += __shfl_down(ht, off, 64);
    if ((tid & 63) == 0) shy[tid >> 6] = ht;
    __syncthreads();

    if (tid == 0) {
        double S  = (sred[0] + sred[1]) + (sred[2] + sred[3]);
        double Hy = (shy[0]  + shy[1])  + (shy[2]  + shy[3]);
        // loss = 0.5*(0.25*S/4096 + S/4096) = 0.625 * S / 4096
        outp[0] = (float)(0.625 * S / 4096.0);
        outp[1] = (float)(-Hy);
        outp[2] = 0.0f;
    }
}

extern "C" void kernel_launch(void* const* d_in, const int* in_sizes, int n_in,
                              void* d_out, int out_size, void* d_ws, size_t ws_size,
                              hipStream_t stream)
{
    const float* q  = (const float*)d_in[0];
    const float* cb = (const float*)d_in[1];
    float* out = (float*)d_out;

    float* emb = out;                     // [B,D,H,W]
    float* yf  = out + Y_OFF;             // [B,H,W] as float
    float* rep = out + REP_OFF;           // [B,H,W,K]
    float* sc  = out + LOSS_OFF;          // loss, Hy, Hyx

    int*   hist    = (int*)d_ws;          // 256 ints
    float* partial = (float*)d_ws + 256;  // 512 floats

    hipMemsetAsync(d_ws, 0, 1024, stream);   // zero hist
    vq_fused_kernel<<<NBLK, 256, 0, stream>>>(q, cb, emb, yf, rep, hist, partial);
    vq_final_kernel<<<1, 256, 0, stream>>>(partial, hist, sc);
}

// Round 4
// 128.084 us; speedup vs baseline: 1.2796x; 1.1987x over previous
//
#include <hip/hip_runtime.h>

#define DD 8
#define HW 16384
#define KK 256
#define NPIX 524288
#define NBLK 2048                      // 256 pixels per block, 1 px/thread

#define Y_OFF    4194304UL             // B*D*H*W
#define REP_OFF  4718592UL             // + B*H*W
#define LOSS_OFF 138936320UL           // + B*H*W*K

typedef float f4 __attribute__((ext_vector_type(4)));

// ---------------- prep: zero hist + precompute ||c||^2 ----------------
__global__ __launch_bounds__(256) void vq_prep_kernel(
    const float* __restrict__ cb, float* __restrict__ c2t, int* __restrict__ hist)
{
    const int k = threadIdx.x;
    const float* c = cb + k*DD;
    c2t[k] = ((c[0]*c[0] + c[1]*c[1]) + (c[2]*c[2] + c[3]*c[3]))
           + ((c[4]*c[4] + c[5]*c[5]) + (c[6]*c[6] + c[7]*c[7]));
    hist[k] = 0;
}

// ---------------- fused: argmax (scalar-load codebook) + folded one-hot ----------------
__global__ __launch_bounds__(256) void vq_fused_kernel(
    const float* __restrict__ q, const float* __restrict__ cb,
    const float* __restrict__ c2t,
    float* __restrict__ emb, float* __restrict__ yf, float* __restrict__ rep,
    int* __restrict__ hist, float* __restrict__ partial)
{
    __shared__ int   sy[256];
    __shared__ int   shist[KK];
    __shared__ float swred[4];

    const int tid = threadIdx.x;
    shist[tid] = 0;

    const int pixBase = blockIdx.x << 8;
    const int b   = pixBase >> 14;          // image index (block within one image)
    const int hwB = pixBase & (HW - 1);
    const int hw  = hwB + tid;
    const float* qb = q + (size_t)b * (DD*HW);

    float xs[DD];
#pragma unroll
    for (int d = 0; d < DD; ++d) xs[d] = qb[d*HW + hw];
    const float xn = ((xs[0]*xs[0] + xs[1]*xs[1]) + (xs[2]*xs[2] + xs[3]*xs[3]))
                   + ((xs[4]*xs[4] + xs[5]*xs[5]) + (xs[6]*xs[6] + xs[7]*xs[7]));

    // t = (x2 - 2xc) + c2 with strict <  ==  reference -0.5*t with strict >
    float best = 3.4e38f;
    int   yb   = 0;
#pragma unroll 4
    for (int k = 0; k < KK; ++k) {
        // lane-invariant addresses -> s_load (SMEM pipe), no LDS, no vector loads
        const f4 c01 = *(const f4*)(cb + (k << 3));
        const f4 c23 = *(const f4*)(cb + (k << 3) + 4);
        const float c2k = c2t[k];
        float dot = 0.f;
        dot = fmaf(xs[0], c01.x, dot);
        dot = fmaf(xs[1], c01.y, dot);
        dot = fmaf(xs[2], c01.z, dot);
        dot = fmaf(xs[3], c01.w, dot);
        dot = fmaf(xs[4], c23.x, dot);
        dot = fmaf(xs[5], c23.y, dot);
        dot = fmaf(xs[6], c23.z, dot);
        dot = fmaf(xs[7], c23.w, dot);
        const float t = (xn - 2.0f*dot) + c2k;
        if (t < best) { best = t; yb = k; }   // first index wins ties
    }

    // per-pixel outputs: emb (gather codebook[yb]), y, err
    float err;
    {
        const f4 cy01 = *(const f4*)(cb + (yb << 3));
        const f4 cy23 = *(const f4*)(cb + (yb << 3) + 4);
        float cyv[DD] = {cy01.x, cy01.y, cy01.z, cy01.w,
                         cy23.x, cy23.y, cy23.z, cy23.w};
        float e = 0.f;
        float* eb = emb + (size_t)b * (DD*HW) + hw;
#pragma unroll
        for (int d = 0; d < DD; ++d) {
            eb[d*HW] = cyv[d];
            const float dd = cyv[d] - xs[d];
            e = fmaf(dd, dd, e);
        }
        err = e;
        yf[pixBase + tid] = (float)yb;
        sy[tid] = yb;
        atomicAdd(&shist[yb], 1);
    }

    // deterministic wave reduction of err (finalized before the barrier)
#pragma unroll
    for (int off = 32; off; off >>= 1)
        err += __shfl_down(err, off, 64);
    if ((tid & 63) == 0) swred[tid >> 6] = err;

    __syncthreads();   // sy/shist/swred ready; phase 2 below

    // phase 2: stream the one-hot rows, 1.0 folded into the store value
    const int wid = tid >> 6;
    const int j   = tid & 63;            // float4 chunk within a row
    const int b4  = j << 2;
    f4* repb = (f4*)rep + (size_t)pixBase * (KK/4);
#pragma unroll 4
    for (int r = wid; r < 256; r += 4) {
        const int y = sy[r];             // wave-uniform LDS broadcast
        f4 v;
        v.x = (y == b4    ) ? 1.0f : 0.0f;
        v.y = (y == b4 + 1) ? 1.0f : 0.0f;
        v.z = (y == b4 + 2) ? 1.0f : 0.0f;
        v.w = (y == b4 + 3) ? 1.0f : 0.0f;
        __builtin_nontemporal_store(v, repb + (size_t)r * (KK/4) + j);
    }

    if (tid == 0)
        partial[blockIdx.x] = (swred[0] + swred[1]) + (swred[2] + swred[3]);
    atomicAdd(&hist[tid], shist[tid]);
}

// ---------------- finalize scalars ----------------
__global__ __launch_bounds__(256) void vq_final_kernel(
    const float* __restrict__ partial, const int* __restrict__ hist,
    float* __restrict__ outp)
{
    const int tid = threadIdx.x;
    __shared__ double sred[4];
    __shared__ double shy[4];

    double s = 0.0;
#pragma unroll
    for (int i = 0; i < 8; ++i) s += (double)partial[tid * 8 + i];
#pragma unroll
    for (int off = 32; off; off >>= 1)
        s += __shfl_down(s, off, 64);
    if ((tid & 63) == 0) sred[tid >> 6] = s;

    float c  = (float)hist[tid];
    float py = c * (1.0f / 524288.0f);
    double ht = (double)(py * log2f(py + 1e-10f));
#pragma unroll
    for (int off = 32; off; off >>= 1)
        ht += __shfl_down(ht, off, 64);
    if ((tid & 63) == 0) shy[tid >> 6] = ht;
    __syncthreads();

    if (tid == 0) {
        double S  = (sred[0] + sred[1]) + (sred[2] + sred[3]);
        double Hy = (shy[0]  + shy[1])  + (shy[2]  + shy[3]);
        // loss = 0.5*(0.25*S/4096 + S/4096) = 0.625 * S / 4096
        outp[0] = (float)(0.625 * S / 4096.0);
        outp[1] = (float)(-Hy);
        outp[2] = 0.0f;
    }
}

extern "C" void kernel_launch(void* const* d_in, const int* in_sizes, int n_in,
                              void* d_out, int out_size, void* d_ws, size_t ws_size,
                              hipStream_t stream)
{
    const float* q  = (const float*)d_in[0];
    const float* cb = (const float*)d_in[1];
    float* out = (float*)d_out;

    float* emb = out;                     // [B,D,H,W]
    float* yf  = out + Y_OFF;             // [B,H,W] as float
    float* rep = out + REP_OFF;           // [B,H,W,K]
    float* sc  = out + LOSS_OFF;          // loss, Hy, Hyx

    float* w       = (float*)d_ws;
    int*   hist    = (int*)w;             // 256 ints
    float* partial = w + 256;             // 2048 floats
    float* c2t     = w + 256 + 2048;      // 256 floats

    vq_prep_kernel<<<1, 256, 0, stream>>>(cb, c2t, hist);
    vq_fused_kernel<<<NBLK, 256, 0, stream>>>(q, cb, c2t, emb, yf, rep, hist, partial);
    vq_final_kernel<<<1, 256, 0, stream>>>(partial, hist, sc);
}